// Round 6
// baseline (286.120 us; speedup 1.0000x reference)
//
#include <hip/hip_runtime.h>
#include <hip/hip_bf16.h>
#include <math.h>

// Problem constants (FusedRoutedMLP)
#define E    8
#define H    1024
#define I2   2816          // 2*I
#define II   1408          // I
#define T    2048
#define KTOP 2
#define NP   (T * KTOP)    // 4096 (token, expert-slot) pairs

// GEMM tiling
#define BM   128           // pair-rows per block (both GEMMs)
#define BK   32            // bf16 K-step (one 16x16x32 MFMA K)
#define BNA  64            // act cols per gemm1 block (=> 128 B-cols: gate+up)
#define BN2  128           // out cols per gemm2 block
#define GX   40            // grid.x upper bound: 4096/128 + 8

// prep kernel block ranges: [route | cvt_x | w1 transpose | w2 transpose]
#define CVT_BLKS  1024                 // (T*H)/(256*8)
#define W1_PER_E  (4 * 44)             // kstrips(1024/256) x ncols(2816/64)
#define W1_BLKS   (W1_PER_E * E)       // 1408
#define W2_PER_E  (11 * 16)            // kstrips(1408/128) x ncols(1024/64)
#define W2_BLKS   (W2_PER_E * E)       // 1408
#define PREP_BLKS (1 + CVT_BLKS + W1_BLKS + W2_BLKS)   // 3841

typedef __attribute__((ext_vector_type(8))) short  short8v;   // 8 bf16 = 4 VGPR
typedef __attribute__((ext_vector_type(4))) float  f32x4;
typedef __attribute__((ext_vector_type(8))) unsigned short ushort8;

__device__ __forceinline__ void gload16(void* lds, const void* g) {
    // async global->LDS, 16B per lane; LDS dest = wave-uniform base + lane*16
    __builtin_amdgcn_global_load_lds((const __attribute__((address_space(1))) unsigned int*)g,
                                     (__attribute__((address_space(3))) unsigned int*)lds,
                                     16, 0, 0);
}

// ---------------------------------------------------------------------------
// prep v2: fused {route (ballot sort) | x->bf16 | w1 transpose | w2 transpose}
// Transpose: bf16-in-LDS, XOR-swizzled (byte ^= (row&7)<<4), pipelined pairs.
// ---------------------------------------------------------------------------
union PrepShared {
    char tiles[2][8192];                       // two 64x64 bf16 tiles
    struct { int cnt4[4][E]; int woff[4][E]; } rt;
};

// load one 64x64 fp32 tile (rows krow0..+63, cols n0..+63) into 4 float4/thread
__device__ __forceinline__ void tr_load(const float* __restrict__ src, int K, int N,
                                        int e, int n0, int krow0, int tid, float4* f)
{
    const float* s = src + (size_t)e * K * N + (size_t)(krow0 + (tid >> 2)) * N
                     + n0 + (tid & 3) * 16;
    f[0] = *(const float4*)(s);
    f[1] = *(const float4*)(s + 4);
    f[2] = *(const float4*)(s + 8);
    f[3] = *(const float4*)(s + 12);
}

// convert + write thread's 16 floats as bf16 into swizzled LDS tile
__device__ __forceinline__ void tr_write(char* lds, int tid, const float4* f)
{
    alignas(16) __hip_bfloat16 t[16];
#pragma unroll
    for (int i = 0; i < 4; ++i) {
        t[4 * i + 0] = __float2bfloat16(f[i].x);
        t[4 * i + 1] = __float2bfloat16(f[i].y);
        t[4 * i + 2] = __float2bfloat16(f[i].z);
        t[4 * i + 3] = __float2bfloat16(f[i].w);
    }
    int r  = tid >> 2;
    int cb = (tid & 3) * 32;            // byte col base (16 bf16 = 32B)
    int sw = (r & 7) << 4;
    *(ushort8*)(lds + r * 128 + ((cb)      ^ sw)) = ((ushort8*)t)[0];
    *(ushort8*)(lds + r * 128 + ((cb + 16) ^ sw)) = ((ushort8*)t)[1];
}

// read both resident tiles col-major and store k-contiguous 64B per thread
__device__ __forceinline__ void tr_store(const char* lds0, const char* lds1,
                                         __hip_bfloat16* __restrict__ dst, int K, int N,
                                         int e, int n0, int kdst0, int tid)
{
    int g  = tid >> 7;                  // which tile (wave-uniform)
    int h  = tid & 127;
    int n  = h >> 1;                    // 0..63 dst row within strip
    int kb = 32 * (h & 1);              // 0 or 32 within tile
    const char* lds = g ? lds1 : lds0;
    alignas(16) __hip_bfloat16 t[32];
#pragma unroll
    for (int j = 0; j < 32; ++j) {
        int r = kb + j;
        t[j] = *(const __hip_bfloat16*)(lds + r * 128 + ((2 * n) ^ ((r & 7) << 4)));
    }
    __hip_bfloat16* d = dst + (size_t)e * K * N + (size_t)(n0 + n) * K + kdst0 + 64 * g + kb;
    *(ushort8*)(d)      = ((ushort8*)t)[0];
    *(ushort8*)(d + 8)  = ((ushort8*)t)[1];
    *(ushort8*)(d + 16) = ((ushort8*)t)[2];
    *(ushort8*)(d + 24) = ((ushort8*)t)[3];
}

// transpose a 64-col x (128*np)-k strip; np = 1 or 2 pairs of 64x64 tiles
__device__ __forceinline__ void tr_strip(const float* __restrict__ src,
                                         __hip_bfloat16* __restrict__ dst,
                                         int K, int N, int e, int n0, int k0,
                                         int np, PrepShared& sh, int tid)
{
    float4 fa0[4], fb0[4], fa1[4], fb1[4];
    tr_load(src, K, N, e, n0, k0,      tid, fa0);
    tr_load(src, K, N, e, n0, k0 + 64, tid, fb0);
    if (np == 2) {
        tr_load(src, K, N, e, n0, k0 + 128, tid, fa1);
        tr_load(src, K, N, e, n0, k0 + 192, tid, fb1);
    }
    tr_write(sh.tiles[0], tid, fa0);
    tr_write(sh.tiles[1], tid, fb0);
    __syncthreads();
    tr_store(sh.tiles[0], sh.tiles[1], dst, K, N, e, n0, k0, tid);
    if (np == 2) {
        __syncthreads();
        tr_write(sh.tiles[0], tid, fa1);
        tr_write(sh.tiles[1], tid, fb1);
        __syncthreads();
        tr_store(sh.tiles[0], sh.tiles[1], dst, K, N, e, n0, k0 + 128, tid);
    }
}

__launch_bounds__(256)
__global__ void prep_kernel(const float* __restrict__ x, const float* __restrict__ w1,
                            const float* __restrict__ w2, const int* __restrict__ ids,
                            __hip_bfloat16* __restrict__ xb,
                            __hip_bfloat16* __restrict__ w1t,
                            __hip_bfloat16* __restrict__ w2t,
                            int* __restrict__ tok, int* __restrict__ inv,
                            int* __restrict__ seg_off, int* __restrict__ tile_off)
{
    __shared__ PrepShared sh;
    int tid = threadIdx.x;
    int b = blockIdx.x;

    if (b == 0) {
        // ---- routing: ballot-based counting sort, no LDS atomics ----
        int lane = tid & 63;
        int w    = tid >> 6;
        unsigned long long ltm = (1ull << lane) - 1ull;

        int wc = 0;                     // lane ee<8 accumulates per-wave count
#pragma unroll 1
        for (int it = 0; it < 16; ++it) {
            int p = it * 256 + w * 64 + lane;
            int e = ids[p];
#pragma unroll
            for (int ee = 0; ee < E; ++ee) {
                unsigned long long m = __ballot(e == ee);
                if (lane == ee) wc += (int)__popcll(m);
            }
        }
        if (lane < E) sh.rt.cnt4[w][lane] = wc;
        __syncthreads();
        if (tid == 0) {
            int base = 0, tiles = 0;
            for (int e = 0; e < E; ++e) {
                seg_off[e]  = base;
                tile_off[e] = tiles;
                int tot = 0;
                for (int ww = 0; ww < 4; ++ww) {
                    sh.rt.woff[ww][e] = base + tot;
                    tot += sh.rt.cnt4[ww][e];
                }
                base  += tot;
                tiles += (tot + BM - 1) / BM;
            }
            seg_off[E]  = base;
            tile_off[E] = tiles;
        }
        __syncthreads();
        int run = (lane < E) ? sh.rt.woff[w][lane] : 0;
#pragma unroll 1
        for (int it = 0; it < 16; ++it) {
            int p = it * 256 + w * 64 + lane;
            int e = ids[p];
            unsigned long long me = 0;
            int acnt = 0;
#pragma unroll
            for (int ee = 0; ee < E; ++ee) {
                unsigned long long m = __ballot(e == ee);
                if (e == ee) me = m;
                if (lane == ee) acnt = (int)__popcll(m);
            }
            int rank = (int)__popcll(me & ltm);
            int qb   = __shfl(run, e, 64);
            int q    = qb + rank;
            tok[q] = p >> 1;
            inv[p] = q;
            run += acnt;
        }
        return;
    }
    b -= 1;

    if (b < CVT_BLKS) {
        // ---- x fp32 -> bf16, 8 elems/thread ----
        int i = (b * 256 + tid) * 8;
        float4 a = *(const float4*)(x + i);
        float4 c = *(const float4*)(x + i + 4);
        alignas(16) __hip_bfloat16 t[8];
        t[0] = __float2bfloat16(a.x); t[1] = __float2bfloat16(a.y);
        t[2] = __float2bfloat16(a.z); t[3] = __float2bfloat16(a.w);
        t[4] = __float2bfloat16(c.x); t[5] = __float2bfloat16(c.y);
        t[6] = __float2bfloat16(c.z); t[7] = __float2bfloat16(c.w);
        *(ushort8*)(xb + i) = *(ushort8*)t;
        return;
    }
    b -= CVT_BLKS;

    if (b < W1_BLKS) {
        int e = b / W1_PER_E, r = b % W1_PER_E;
        tr_strip(w1, w1t, H, I2, e, (r % 44) * 64, (r / 44) * 256, 2, sh, tid);
        return;
    }
    b -= W1_BLKS;
    {
        int e = b / W2_PER_E, r = b % W2_PER_E;
        tr_strip(w2, w2t, II, H, e, (r % 16) * 64, (r / 16) * 128, 1, sh, tid);
    }
}

// ---------------------------------------------------------------------------
// GEMM1 + SiLU (bf16 MFMA): act[p, 0:64@jb] = silu(x.w1g) * (x.w1u)
// Tile: 128 rows x 64 act-cols (=> gate 64 + up 64 B-cols), 4 waves 2x2.
// ---------------------------------------------------------------------------
__launch_bounds__(256, 2)
__global__ void gemm1_silu(const __hip_bfloat16* __restrict__ xb,
                           const __hip_bfloat16* __restrict__ w1t,   // [e][n=2816][k=1024]
                           const int* __restrict__ tok,
                           const int* __restrict__ seg_off,
                           const int* __restrict__ tile_off,
                           __hip_bfloat16* __restrict__ act)         // [p][1408]
{
    __shared__ __align__(16) __hip_bfloat16 As[BM * BK];    // [row][k] 8KB
    __shared__ __align__(16) __hip_bfloat16 Bg[BNA * BK];   // [col][k] 4KB
    __shared__ __align__(16) __hip_bfloat16 Bu[BNA * BK];   // 4KB
    __shared__ int tokS[BM];

    int bx = blockIdx.x;
    if (bx >= tile_off[E]) return;
    int e = 0;
#pragma unroll
    for (int i = 1; i < E; ++i) if (bx >= tile_off[i]) e = i;
    int row0 = seg_off[e] + (bx - tile_off[e]) * BM;
    int rend = seg_off[e + 1];
    int jb   = blockIdx.y * BNA;

    int tid = threadIdx.x;
    if (tid < BM) {
        int gr = row0 + tid;
        tokS[tid] = tok[gr < NP ? gr : NP - 1];
    }
    __syncthreads();

    // staging addresses: thread covers 16B; row = tid/4, byte-in-row = (tid&3)*16
    int arow = tid >> 2;
    int aoff = (tid & 3) * 16;
    const char* xB  = (const char*)xb;
    const char* w1B = (const char*)(w1t + (size_t)e * I2 * H);
    const char* srcA0 = xB + (size_t)tokS[arow]      * 2048 + aoff;   // rows 0..63
    const char* srcA1 = xB + (size_t)tokS[arow + 64] * 2048 + aoff;   // rows 64..127
    const char* srcG  = w1B + (size_t)(jb + arow)      * 2048 + aoff;
    const char* srcU  = w1B + (size_t)(II + jb + arow) * 2048 + aoff;
    __hip_bfloat16* dA0 = &As[tid * 8];
    __hip_bfloat16* dA1 = &As[2048 + tid * 8];
    __hip_bfloat16* dG  = &Bg[tid * 8];
    __hip_bfloat16* dU  = &Bu[tid * 8];

    int lane = tid & 63;
    int w  = tid >> 6;
    int wm = w >> 1, wn = w & 1;   // wave region: rows wm*64, act-cols wn*32
    int fr = lane & 15;            // fragment row/col
    int kc = lane >> 4;            // k-chunk (8 elems each)

    f32x4 accg[4][2] = {};
    f32x4 accu[4][2] = {};
    const short8v* Asv = (const short8v*)As;
    const short8v* Bgv = (const short8v*)Bg;
    const short8v* Buv = (const short8v*)Bu;

    for (int k0 = 0; k0 < H; k0 += BK) {
        gload16(dA0, srcA0);
        gload16(dA1, srcA1);
        gload16(dG, srcG);
        gload16(dU, srcU);
        srcA0 += 64; srcA1 += 64; srcG += 64; srcU += 64;
        __syncthreads();   // drains vmcnt before LDS reads

        short8v a[4], g[2], u[2];
#pragma unroll
        for (int m = 0; m < 4; ++m)
            a[m] = Asv[(wm * 64 + m * 16 + fr) * 4 + kc];
#pragma unroll
        for (int n = 0; n < 2; ++n) {
            g[n] = Bgv[(wn * 32 + n * 16 + fr) * 4 + kc];
            u[n] = Buv[(wn * 32 + n * 16 + fr) * 4 + kc];
        }
#pragma unroll
        for (int m = 0; m < 4; ++m)
#pragma unroll
            for (int n = 0; n < 2; ++n) {
                accg[m][n] = __builtin_amdgcn_mfma_f32_16x16x32_bf16(a[m], g[n], accg[m][n], 0, 0, 0);
                accu[m][n] = __builtin_amdgcn_mfma_f32_16x16x32_bf16(a[m], u[n], accu[m][n], 0, 0, 0);
            }
        __syncthreads();
    }

    // epilogue: silu(gate)*up -> bf16 act.  C/D layout: col=lane&15, row=(lane>>4)*4+j
#pragma unroll
    for (int m = 0; m < 4; ++m)
#pragma unroll
        for (int n = 0; n < 2; ++n) {
            int col = jb + wn * 32 + n * 16 + fr;
#pragma unroll
            for (int j = 0; j < 4; ++j) {
                int gr = row0 + wm * 64 + m * 16 + kc * 4 + j;
                if (gr < rend) {
                    float gg = accg[m][n][j];
                    float s  = gg / (1.0f + __expf(-gg));
                    act[(size_t)gr * II + col] = __float2bfloat16(s * accu[m][n][j]);
                }
            }
        }
}

// ---------------------------------------------------------------------------
// GEMM2: y[q] = act[q] . w2[e]   (plain stores, rows dense in sorted order)
// Tile: 128 rows x 128 cols, 4 waves 2x2, K=1408.
// ---------------------------------------------------------------------------
__launch_bounds__(256, 2)
__global__ void gemm2(const __hip_bfloat16* __restrict__ act,
                      const __hip_bfloat16* __restrict__ w2t,  // [e][n=1024][k=1408]
                      const int* __restrict__ seg_off,
                      const int* __restrict__ tile_off,
                      float* __restrict__ y)                   // [q][1024]
{
    __shared__ __align__(16) __hip_bfloat16 As[BM * BK];     // 8KB
    __shared__ __align__(16) __hip_bfloat16 Bs[BN2 * BK];    // 8KB

    int bx = blockIdx.x;
    if (bx >= tile_off[E]) return;
    int e = 0;
#pragma unroll
    for (int i = 1; i < E; ++i) if (bx >= tile_off[i]) e = i;
    int row0 = seg_off[e] + (bx - tile_off[e]) * BM;
    int rend = seg_off[e + 1];
    int nb   = blockIdx.y * BN2;

    int tid = threadIdx.x;
    int arow = tid >> 2;
    int aoff = (tid & 3) * 16;
    const char* actB = (const char*)act;
    const char* w2B  = (const char*)(w2t + (size_t)e * H * II);
    int r0c = row0 + arow;       r0c = r0c < NP ? r0c : NP - 1;
    int r1c = row0 + arow + 64;  r1c = r1c < NP ? r1c : NP - 1;
    const char* srcA0 = actB + (size_t)r0c * 2816 + aoff;
    const char* srcA1 = actB + (size_t)r1c * 2816 + aoff;
    const char* srcB0 = w2B + (size_t)(nb + arow)      * 2816 + aoff;
    const char* srcB1 = w2B + (size_t)(nb + arow + 64) * 2816 + aoff;
    __hip_bfloat16* dA0 = &As[tid * 8];
    __hip_bfloat16* dA1 = &As[2048 + tid * 8];
    __hip_bfloat16* dB0 = &Bs[tid * 8];
    __hip_bfloat16* dB1 = &Bs[2048 + tid * 8];

    int lane = tid & 63;
    int w  = tid >> 6;
    int wm = w >> 1, wn = w & 1;   // wave region: rows wm*64, cols wn*64
    int fr = lane & 15;
    int kc = lane >> 4;

    f32x4 acc[4][4] = {};
    const short8v* Asv = (const short8v*)As;
    const short8v* Bsv = (const short8v*)Bs;

    for (int k0 = 0; k0 < II; k0 += BK) {
        gload16(dA0, srcA0);
        gload16(dA1, srcA1);
        gload16(dB0, srcB0);
        gload16(dB1, srcB1);
        srcA0 += 64; srcA1 += 64; srcB0 += 64; srcB1 += 64;
        __syncthreads();

        short8v a[4], b[4];
#pragma unroll
        for (int m = 0; m < 4; ++m)
            a[m] = Asv[(wm * 64 + m * 16 + fr) * 4 + kc];
#pragma unroll
        for (int n = 0; n < 4; ++n)
            b[n] = Bsv[(wn * 64 + n * 16 + fr) * 4 + kc];
#pragma unroll
        for (int m = 0; m < 4; ++m)
#pragma unroll
            for (int n = 0; n < 4; ++n)
                acc[m][n] = __builtin_amdgcn_mfma_f32_16x16x32_bf16(a[m], b[n], acc[m][n], 0, 0, 0);
        __syncthreads();
    }

#pragma unroll
    for (int m = 0; m < 4; ++m)
#pragma unroll
        for (int n = 0; n < 4; ++n) {
            int col = nb + wn * 64 + n * 16 + fr;
#pragma unroll
            for (int j = 0; j < 4; ++j) {
                int lr = wm * 64 + m * 16 + kc * 4 + j;
                int gr = row0 + lr;
                if (gr < rend)
                    y[(size_t)gr * H + col] = acc[m][n][j];
            }
        }
}

// ---------------------------------------------------------------------------
// gather: out[t] = rw[t,0] * y[inv[2t]] + rw[t,1] * y[inv[2t+1]]
// ---------------------------------------------------------------------------
__global__ void gather_out(const float* __restrict__ y, const int* __restrict__ inv,
                           const float* __restrict__ rw, float* __restrict__ out)
{
    int gid = blockIdx.x * 256 + threadIdx.x;     // 524288 threads, float4 each
    int t = gid >> 8;                              // 256 float4 groups per token
    int c = (gid & 255) * 4;
    int q0 = inv[2 * t], q1 = inv[2 * t + 1];
    float w0 = rw[2 * t], w1 = rw[2 * t + 1];
    float4 a = *(const float4*)(y + (size_t)q0 * H + c);
    float4 b = *(const float4*)(y + (size_t)q1 * H + c);
    float4 o;
    o.x = w0 * a.x + w1 * b.x;
    o.y = w0 * a.y + w1 * b.y;
    o.z = w0 * a.z + w1 * b.z;
    o.w = w0 * a.w + w1 * b.w;
    *(float4*)(out + (size_t)t * H + c) = o;
}

// ---------------------------------------------------------------------------
extern "C" void kernel_launch(void* const* d_in, const int* in_sizes, int n_in,
                              void* d_out, int out_size, void* d_ws, size_t ws_size,
                              hipStream_t stream)
{
    const float* x   = (const float*)d_in[0];
    const int*   ids = (const int*)d_in[1];
    const float* rw  = (const float*)d_in[2];
    const float* w1  = (const float*)d_in[3];
    const float* w2  = (const float*)d_in[4];
    float*       out = (float*)d_out;

    char* ws = (char*)d_ws;
    int*   tok  = (int*)ws;                              // 16 KB
    int*   inv  = (int*)(ws + 16384);                    // 16 KB
    int*   seg  = (int*)(ws + 32768);                    // E+1
    int*   tile = (int*)(ws + 32768 + 64);               // E+1
    __hip_bfloat16* xb  = (__hip_bfloat16*)(ws + 65536);                    // 4 MB
    __hip_bfloat16* w1t = (__hip_bfloat16*)(ws + 4259840);                  // 46.1 MB
    __hip_bfloat16* w2t = (__hip_bfloat16*)(ws + 50397184);                 // 23.1 MB
    __hip_bfloat16* act = (__hip_bfloat16*)(ws + 73465856);                 // 11.5 MB
    float*          y   = (float*)(ws + 85000192);                          // 16 MB

    prep_kernel<<<PREP_BLKS, 256, 0, stream>>>(x, w1, w2, ids, xb, w1t, w2t,
                                               tok, inv, seg, tile);

    gemm1_silu<<<dim3(GX, II / BNA), 256, 0, stream>>>(xb, w1t, tok, seg, tile, act);  // (40,22)
    gemm2<<<dim3(GX, H / BN2), 256, 0, stream>>>(act, w2t, seg, tile, y);              // (40,8)
    gather_out<<<(T * H) / (256 * 4), 256, 0, stream>>>(y, inv, rw, out);              // 2048 blocks
}

// Round 7
// 285.316 us; speedup vs baseline: 1.0028x; 1.0028x over previous
//
#include <hip/hip_runtime.h>
#include <hip/hip_bf16.h>
#include <math.h>

// Problem constants (FusedRoutedMLP)
#define E    8
#define H    1024
#define I2   2816          // 2*I
#define II   1408          // I
#define T    2048
#define KTOP 2
#define NP   (T * KTOP)    // 4096 (token, expert-slot) pairs

// GEMM tiling
#define BM   128           // pair-rows per block (both GEMMs)
#define BK   32            // bf16 K-step (one 16x16x32 MFMA K)
#define BNA  64            // act cols per gemm1 block (=> 128 B-cols: gate+up)
#define BN2  128           // out cols per gemm2 block
#define GX   40            // gemm1/2 row-tile grid bound: 4096/128 + 8
#define GXT  8             // extra gemm1 bx slots for the w2 transpose

// prep kernel block ranges: [route | cvt_x | w1 transpose tiles]
#define CVT_BLKS  1024                  // (T*H)/(256*8)
#define W1_TILES  (16 * 44 * E)         // 5632 64x64 tiles
#define PREP_BLKS (1 + CVT_BLKS + W1_TILES)

// w2 transpose inside gemm1 tail blocks
#define W2_TILES     2816               // 22 * 16 * E
#define W2_BLOCKS    (GXT * 22)         // 176
#define W2_PER_BLOCK (W2_TILES / W2_BLOCKS)   // 16

typedef __attribute__((ext_vector_type(8))) short  short8v;   // 8 bf16 = 4 VGPR
typedef __attribute__((ext_vector_type(4))) float  f32x4;
typedef __attribute__((ext_vector_type(8))) unsigned short ushort8;

__device__ __forceinline__ void gload16(void* lds, const void* g) {
    // async global->LDS, 16B per lane; LDS dest = wave-uniform base + lane*16
    __builtin_amdgcn_global_load_lds((const __attribute__((address_space(1))) unsigned int*)g,
                                     (__attribute__((address_space(3))) unsigned int*)lds,
                                     16, 0, 0);
}

// ---------------------------------------------------------------------------
// Async-staged 64x64 transpose+convert tile.
//  src: expert base of [K][N] fp32 (rows k, cols n), tile at (k0, n0)
//  dst: expert base of [N][K] bf16
// Staging: global_load_lds into LINEAR fp32 LDS tile; per rule #21 the
// 16B-chunk source index is swizzled (c16 ^= r&15) and the LDS read applies
// the same swizzle, spreading the column read across 8 banks instead of 1.
// ---------------------------------------------------------------------------
__device__ __forceinline__ void transpose_tile_async(
    const float* __restrict__ src, __hip_bfloat16* __restrict__ dst,
    int K, int N, int k0, int n0, float* tile, int tid)
{
    int lane = tid & 63;
    int wv   = tid >> 6;
#pragma unroll
    for (int i = 0; i < 4; ++i) {
        int q   = (wv * 4 + i) * 64 + lane;   // LDS 16B-chunk index 0..1023
        int r   = q >> 4;                     // tile row (k)
        int c16 = q & 15;                     // chunk within row
        const float* gsrc = src + (size_t)(k0 + r) * N + n0 + ((c16 ^ (r & 15)) << 2);
        gload16(tile + q * 4, gsrc);
    }
    __syncthreads();    // drains vmcnt before LDS reads

    int n  = tid >> 2;              // output row (source col) 0..63
    int ks = (tid & 3) * 16;        // k-segment within tile
    alignas(16) __hip_bfloat16 t[16];
#pragma unroll
    for (int j = 0; j < 16; ++j) {
        int r = ks + j;
        float v = tile[r * 64 + (((n >> 2) ^ (r & 15)) << 2) + (n & 3)];
        t[j] = __float2bfloat16(v);
    }
    __hip_bfloat16* d = dst + (size_t)(n0 + n) * K + k0 + ks;
    *(ushort8*)(d)     = ((ushort8*)t)[0];
    *(ushort8*)(d + 8) = ((ushort8*)t)[1];
}

// ---------------------------------------------------------------------------
// prep v3: {route (ballot sort) | x->bf16 | w1 transpose (async tiles)}
// ---------------------------------------------------------------------------
union PrepShared {
    float tile[4096];                          // 16 KB fp32 transpose tile
    struct { int cnt4[4][E]; int woff[4][E]; } rt;
};

__launch_bounds__(256)
__global__ void prep_kernel(const float* __restrict__ x, const float* __restrict__ w1,
                            const int* __restrict__ ids,
                            __hip_bfloat16* __restrict__ xb,
                            __hip_bfloat16* __restrict__ w1t,
                            int* __restrict__ tok, int* __restrict__ inv,
                            int* __restrict__ seg_off, int* __restrict__ tile_off)
{
    __shared__ __align__(16) PrepShared sh;
    int tid = threadIdx.x;
    int b = blockIdx.x;

    if (b == 0) {
        // ---- routing: ballot-based counting sort, no LDS atomics ----
        int lane = tid & 63;
        int w    = tid >> 6;
        unsigned long long ltm = (1ull << lane) - 1ull;

        int wc = 0;                     // lane ee<8 accumulates per-wave count
#pragma unroll 1
        for (int it = 0; it < 16; ++it) {
            int p = it * 256 + w * 64 + lane;
            int e = ids[p];
#pragma unroll
            for (int ee = 0; ee < E; ++ee) {
                unsigned long long m = __ballot(e == ee);
                if (lane == ee) wc += (int)__popcll(m);
            }
        }
        if (lane < E) sh.rt.cnt4[w][lane] = wc;
        __syncthreads();
        if (tid == 0) {
            int base = 0, tiles = 0;
            for (int e = 0; e < E; ++e) {
                seg_off[e]  = base;
                tile_off[e] = tiles;
                int tot = 0;
                for (int ww = 0; ww < 4; ++ww) {
                    sh.rt.woff[ww][e] = base + tot;
                    tot += sh.rt.cnt4[ww][e];
                }
                base  += tot;
                tiles += (tot + BM - 1) / BM;
            }
            seg_off[E]  = base;
            tile_off[E] = tiles;
        }
        __syncthreads();
        int run = (lane < E) ? sh.rt.woff[w][lane] : 0;
#pragma unroll 1
        for (int it = 0; it < 16; ++it) {
            int p = it * 256 + w * 64 + lane;
            int e = ids[p];
            unsigned long long me = 0;
            int acnt = 0;
#pragma unroll
            for (int ee = 0; ee < E; ++ee) {
                unsigned long long m = __ballot(e == ee);
                if (e == ee) me = m;
                if (lane == ee) acnt = (int)__popcll(m);
            }
            int rank = (int)__popcll(me & ltm);
            int qb   = __shfl(run, e, 64);
            int q    = qb + rank;
            tok[q] = p >> 1;
            inv[p] = q;
            run += acnt;
        }
        return;
    }
    b -= 1;

    if (b < CVT_BLKS) {
        // ---- x fp32 -> bf16, 8 elems/thread ----
        int i = (b * 256 + tid) * 8;
        float4 a = *(const float4*)(x + i);
        float4 c = *(const float4*)(x + i + 4);
        alignas(16) __hip_bfloat16 t[8];
        t[0] = __float2bfloat16(a.x); t[1] = __float2bfloat16(a.y);
        t[2] = __float2bfloat16(a.z); t[3] = __float2bfloat16(a.w);
        t[4] = __float2bfloat16(c.x); t[5] = __float2bfloat16(c.y);
        t[6] = __float2bfloat16(c.z); t[7] = __float2bfloat16(c.w);
        *(ushort8*)(xb + i) = *(ushort8*)t;
        return;
    }
    b -= CVT_BLKS;

    // ---- w1 transpose: one 64x64 tile per block ----
    {
        int e = b / 704, r = b % 704;          // 16 kstrips x 44 nstrips
        int k0 = (r / 44) * 64, n0 = (r % 44) * 64;
        transpose_tile_async(w1 + (size_t)e * H * I2, w1t + (size_t)e * I2 * H,
                             H, I2, k0, n0, sh.tile, tid);
    }
}

// ---------------------------------------------------------------------------
// GEMM1 + SiLU (bf16 MFMA): act[p, 0:64@jb] = silu(x.w1g) * (x.w1u)
// Tile: 128 rows x 64 act-cols (=> gate 64 + up 64 B-cols), 4 waves 2x2.
// Tail blocks (bx >= GX) transpose w2 (fp32->bf16 [n][k]) concurrently.
// ---------------------------------------------------------------------------
union Gemm1Shared {
    struct {
        __hip_bfloat16 As[BM * BK];     // 8KB
        __hip_bfloat16 Bg[BNA * BK];    // 4KB
        __hip_bfloat16 Bu[BNA * BK];    // 4KB
        int tokS[BM];
    } g;
    float tile[4096];                   // 16KB w2-transpose staging
};

__launch_bounds__(256, 2)
__global__ void gemm1_silu(const __hip_bfloat16* __restrict__ xb,
                           const __hip_bfloat16* __restrict__ w1t,   // [e][n=2816][k=1024]
                           const float* __restrict__ w2,             // [e][k=1408][n=1024] fp32
                           __hip_bfloat16* __restrict__ w2t,         // [e][n=1024][k=1408]
                           const int* __restrict__ tok,
                           const int* __restrict__ seg_off,
                           const int* __restrict__ tile_off,
                           __hip_bfloat16* __restrict__ act)         // [p][1408]
{
    __shared__ __align__(16) Gemm1Shared sh;
    int tid = threadIdx.x;
    int bx = blockIdx.x;

    if (bx >= GX) {
        // ---- w2 transpose tail: 16 tiles per block, hidden under MFMA ----
        int wid = (bx - GX) * 22 + blockIdx.y;        // 0..175
#pragma unroll 1
        for (int i = 0; i < W2_PER_BLOCK; ++i) {
            int t = wid * W2_PER_BLOCK + i;           // 0..2815
            int e = t / 352, r = t % 352;             // 22 kstrips x 16 nstrips
            int k0 = (r >> 4) * 64, n0 = (r & 15) * 64;
            transpose_tile_async(w2 + (size_t)e * II * H, w2t + (size_t)e * H * II,
                                 II, H, k0, n0, sh.tile, tid);
            __syncthreads();
        }
        return;
    }

    if (bx >= tile_off[E]) return;
    int e = 0;
#pragma unroll
    for (int i = 1; i < E; ++i) if (bx >= tile_off[i]) e = i;
    int row0 = seg_off[e] + (bx - tile_off[e]) * BM;
    int rend = seg_off[e + 1];
    int jb   = blockIdx.y * BNA;

    __hip_bfloat16* As = sh.g.As;
    __hip_bfloat16* Bg = sh.g.Bg;
    __hip_bfloat16* Bu = sh.g.Bu;

    if (tid < BM) {
        int gr = row0 + tid;
        sh.g.tokS[tid] = tok[gr < NP ? gr : NP - 1];
    }
    __syncthreads();

    // staging addresses: thread covers 16B; row = tid/4, byte-in-row = (tid&3)*16
    int arow = tid >> 2;
    int aoff = (tid & 3) * 16;
    const char* xB  = (const char*)xb;
    const char* w1B = (const char*)(w1t + (size_t)e * I2 * H);
    const char* srcA0 = xB + (size_t)sh.g.tokS[arow]      * 2048 + aoff;   // rows 0..63
    const char* srcA1 = xB + (size_t)sh.g.tokS[arow + 64] * 2048 + aoff;   // rows 64..127
    const char* srcG  = w1B + (size_t)(jb + arow)      * 2048 + aoff;
    const char* srcU  = w1B + (size_t)(II + jb + arow) * 2048 + aoff;
    __hip_bfloat16* dA0 = &As[tid * 8];
    __hip_bfloat16* dA1 = &As[2048 + tid * 8];
    __hip_bfloat16* dG  = &Bg[tid * 8];
    __hip_bfloat16* dU  = &Bu[tid * 8];

    int lane = tid & 63;
    int w  = tid >> 6;
    int wm = w >> 1, wn = w & 1;   // wave region: rows wm*64, act-cols wn*32
    int fr = lane & 15;            // fragment row/col
    int kc = lane >> 4;            // k-chunk (8 elems each)

    f32x4 accg[4][2] = {};
    f32x4 accu[4][2] = {};
    const short8v* Asv = (const short8v*)As;
    const short8v* Bgv = (const short8v*)Bg;
    const short8v* Buv = (const short8v*)Bu;

    for (int k0 = 0; k0 < H; k0 += BK) {
        gload16(dA0, srcA0);
        gload16(dA1, srcA1);
        gload16(dG, srcG);
        gload16(dU, srcU);
        srcA0 += 64; srcA1 += 64; srcG += 64; srcU += 64;
        __syncthreads();   // drains vmcnt before LDS reads

        short8v a[4], g[2], u[2];
#pragma unroll
        for (int m = 0; m < 4; ++m)
            a[m] = Asv[(wm * 64 + m * 16 + fr) * 4 + kc];
#pragma unroll
        for (int n = 0; n < 2; ++n) {
            g[n] = Bgv[(wn * 32 + n * 16 + fr) * 4 + kc];
            u[n] = Buv[(wn * 32 + n * 16 + fr) * 4 + kc];
        }
#pragma unroll
        for (int m = 0; m < 4; ++m)
#pragma unroll
            for (int n = 0; n < 2; ++n) {
                accg[m][n] = __builtin_amdgcn_mfma_f32_16x16x32_bf16(a[m], g[n], accg[m][n], 0, 0, 0);
                accu[m][n] = __builtin_amdgcn_mfma_f32_16x16x32_bf16(a[m], u[n], accu[m][n], 0, 0, 0);
            }
        __syncthreads();
    }

    // epilogue: silu(gate)*up -> bf16 act.  C/D layout: col=lane&15, row=(lane>>4)*4+j
#pragma unroll
    for (int m = 0; m < 4; ++m)
#pragma unroll
        for (int n = 0; n < 2; ++n) {
            int col = jb + wn * 32 + n * 16 + fr;
#pragma unroll
            for (int j = 0; j < 4; ++j) {
                int gr = row0 + wm * 64 + m * 16 + kc * 4 + j;
                if (gr < rend) {
                    float gg = accg[m][n][j];
                    float s  = gg / (1.0f + __expf(-gg));
                    act[(size_t)gr * II + col] = __float2bfloat16(s * accu[m][n][j]);
                }
            }
        }
}

// ---------------------------------------------------------------------------
// GEMM2: y[q] = act[q] . w2[e]   (plain stores, rows dense in sorted order)
// Tile: 128 rows x 128 cols, 4 waves 2x2, K=1408.
// ---------------------------------------------------------------------------
__launch_bounds__(256, 2)
__global__ void gemm2(const __hip_bfloat16* __restrict__ act,
                      const __hip_bfloat16* __restrict__ w2t,  // [e][n=1024][k=1408]
                      const int* __restrict__ seg_off,
                      const int* __restrict__ tile_off,
                      float* __restrict__ y)                   // [q][1024]
{
    __shared__ __align__(16) __hip_bfloat16 As[BM * BK];     // 8KB
    __shared__ __align__(16) __hip_bfloat16 Bs[BN2 * BK];    // 8KB

    int bx = blockIdx.x;
    if (bx >= tile_off[E]) return;
    int e = 0;
#pragma unroll
    for (int i = 1; i < E; ++i) if (bx >= tile_off[i]) e = i;
    int row0 = seg_off[e] + (bx - tile_off[e]) * BM;
    int rend = seg_off[e + 1];
    int nb   = blockIdx.y * BN2;

    int tid = threadIdx.x;
    int arow = tid >> 2;
    int aoff = (tid & 3) * 16;
    const char* actB = (const char*)act;
    const char* w2B  = (const char*)(w2t + (size_t)e * H * II);
    int r0c = row0 + arow;       r0c = r0c < NP ? r0c : NP - 1;
    int r1c = row0 + arow + 64;  r1c = r1c < NP ? r1c : NP - 1;
    const char* srcA0 = actB + (size_t)r0c * 2816 + aoff;
    const char* srcA1 = actB + (size_t)r1c * 2816 + aoff;
    const char* srcB0 = w2B + (size_t)(nb + arow)      * 2816 + aoff;
    const char* srcB1 = w2B + (size_t)(nb + arow + 64) * 2816 + aoff;
    __hip_bfloat16* dA0 = &As[tid * 8];
    __hip_bfloat16* dA1 = &As[2048 + tid * 8];
    __hip_bfloat16* dB0 = &Bs[tid * 8];
    __hip_bfloat16* dB1 = &Bs[2048 + tid * 8];

    int lane = tid & 63;
    int w  = tid >> 6;
    int wm = w >> 1, wn = w & 1;   // wave region: rows wm*64, cols wn*64
    int fr = lane & 15;
    int kc = lane >> 4;

    f32x4 acc[4][4] = {};
    const short8v* Asv = (const short8v*)As;
    const short8v* Bsv = (const short8v*)Bs;

    for (int k0 = 0; k0 < II; k0 += BK) {
        gload16(dA0, srcA0);
        gload16(dA1, srcA1);
        gload16(dB0, srcB0);
        gload16(dB1, srcB1);
        srcA0 += 64; srcA1 += 64; srcB0 += 64; srcB1 += 64;
        __syncthreads();

        short8v a[4], b[4];
#pragma unroll
        for (int m = 0; m < 4; ++m)
            a[m] = Asv[(wm * 64 + m * 16 + fr) * 4 + kc];
#pragma unroll
        for (int n = 0; n < 4; ++n)
            b[n] = Bsv[(wn * 64 + n * 16 + fr) * 4 + kc];
#pragma unroll
        for (int m = 0; m < 4; ++m)
#pragma unroll
            for (int n = 0; n < 4; ++n)
                acc[m][n] = __builtin_amdgcn_mfma_f32_16x16x32_bf16(a[m], b[n], acc[m][n], 0, 0, 0);
        __syncthreads();
    }

#pragma unroll
    for (int m = 0; m < 4; ++m)
#pragma unroll
        for (int n = 0; n < 4; ++n) {
            int col = nb + wn * 64 + n * 16 + fr;
#pragma unroll
            for (int j = 0; j < 4; ++j) {
                int lr = wm * 64 + m * 16 + kc * 4 + j;
                int gr = row0 + lr;
                if (gr < rend)
                    y[(size_t)gr * H + col] = acc[m][n][j];
            }
        }
}

// ---------------------------------------------------------------------------
// gather: out[t] = rw[t,0] * y[inv[2t]] + rw[t,1] * y[inv[2t+1]]
// ---------------------------------------------------------------------------
__global__ void gather_out(const float* __restrict__ y, const int* __restrict__ inv,
                           const float* __restrict__ rw, float* __restrict__ out)
{
    int gid = blockIdx.x * 256 + threadIdx.x;     // 524288 threads, float4 each
    int t = gid >> 8;                              // 256 float4 groups per token
    int c = (gid & 255) * 4;
    int q0 = inv[2 * t], q1 = inv[2 * t + 1];
    float w0 = rw[2 * t], w1 = rw[2 * t + 1];
    float4 a = *(const float4*)(y + (size_t)q0 * H + c);
    float4 b = *(const float4*)(y + (size_t)q1 * H + c);
    float4 o;
    o.x = w0 * a.x + w1 * b.x;
    o.y = w0 * a.y + w1 * b.y;
    o.z = w0 * a.z + w1 * b.z;
    o.w = w0 * a.w + w1 * b.w;
    *(float4*)(out + (size_t)t * H + c) = o;
}

// ---------------------------------------------------------------------------
extern "C" void kernel_launch(void* const* d_in, const int* in_sizes, int n_in,
                              void* d_out, int out_size, void* d_ws, size_t ws_size,
                              hipStream_t stream)
{
    const float* x   = (const float*)d_in[0];
    const int*   ids = (const int*)d_in[1];
    const float* rw  = (const float*)d_in[2];
    const float* w1  = (const float*)d_in[3];
    const float* w2  = (const float*)d_in[4];
    float*       out = (float*)d_out;

    char* ws = (char*)d_ws;
    int*   tok  = (int*)ws;                              // 16 KB
    int*   inv  = (int*)(ws + 16384);                    // 16 KB
    int*   seg  = (int*)(ws + 32768);                    // E+1
    int*   tile = (int*)(ws + 32768 + 64);               // E+1
    __hip_bfloat16* xb  = (__hip_bfloat16*)(ws + 65536);                    // 4 MB
    __hip_bfloat16* w1t = (__hip_bfloat16*)(ws + 4259840);                  // 46.1 MB
    __hip_bfloat16* w2t = (__hip_bfloat16*)(ws + 50397184);                 // 23.1 MB
    __hip_bfloat16* act = (__hip_bfloat16*)(ws + 73465856);                 // 11.5 MB
    float*          y   = (float*)(ws + 85000192);                          // 16 MB

    prep_kernel<<<PREP_BLKS, 256, 0, stream>>>(x, w1, ids, xb, w1t, tok, inv, seg, tile);

    gemm1_silu<<<dim3(GX + GXT, II / BNA), 256, 0, stream>>>(xb, w1t, w2, w2t,
                                                             tok, seg, tile, act);   // (48,22)
    gemm2<<<dim3(GX, H / BN2), 256, 0, stream>>>(act, w2t, seg, tile, y);            // (40,8)
    gather_out<<<(T * H) / (256 * 4), 256, 0, stream>>>(y, inv, rw, out);            // 2048 blocks
}